// Round 5
// baseline (148.860 us; speedup 1.0000x reference)
//
#include <hip/hip_runtime.h>
#include <hip/hip_bf16.h>

#define N_CLAUSES 50000
#define FEAT_DIM 64
#define EMBED_DIM 128
#define NUM_QUEUES 8
#define NUM_STEPS 2048
#define ENTROPY_COEF 0.1f

#define CHUNK 2048
#define NCHUNK 25   // ceil(50000/2048)
#define SGRP 4
#define KPG 64

typedef unsigned int v4u __attribute__((ext_vector_type(4)));
typedef unsigned int v2u __attribute__((ext_vector_type(2)));

// ---------------- workspace layout (float units) ----------------
#define WS_LOGITS 0                 // [8][50000]
#define WS_ROWMAX 400000            // [8] int-encoded max
#define WS_K2T    400008            // [128][8]
#define WS_CQ     401032            // [8]
#define WS_W1T    401040            // [128][64]
#define WS_FLAG   409232            // int: 1 = byte mask, 0 = int32 mask
#define WS_PART   409248            // [NCHUNK][NUM_STEPS] float4
#define WS_LOSS   (WS_PART + NCHUNK * NUM_STEPS * 4)   // [2048]

// order-preserving float<->int encode for atomicMax on signed int
__device__ inline int enc_f(float f) {
  int b = __float_as_int(f);
  return b >= 0 ? b : (b ^ 0x7FFFFFFF);
}
__device__ inline float dec_f(int k) {
  return __int_as_float(k >= 0 ? k : (k ^ 0x7FFFFFFF));
}

__global__ __launch_bounds__(1024) void k_prep(const float* __restrict__ W1,
    const float* __restrict__ b2, const float* __restrict__ W2,
    const float* __restrict__ keys, const unsigned int* __restrict__ maskw,
    float* __restrict__ W1T, float* __restrict__ K2T, float* __restrict__ cq,
    int* __restrict__ flag, int* __restrict__ rowmax_i) {
  int tid = threadIdx.x;
  __shared__ int sflag;
  if (tid == 0) sflag = 0;
  __syncthreads();
  if (maskw[tid] > 1u) atomicOr(&sflag, 1);
  {
    int q = tid >> 7, j = tid & 127;
    float a = 0.f;
    for (int e = 0; e < EMBED_DIM; ++e)
      a = fmaf(W2[j * EMBED_DIM + e], keys[q * EMBED_DIM + e], a);
    K2T[j * 8 + q] = a;
  }
  if (tid < NUM_QUEUES) {
    float a = 0.f;
    for (int e = 0; e < EMBED_DIM; ++e)
      a = fmaf(b2[e], keys[tid * EMBED_DIM + e], a);
    cq[tid] = a;
    rowmax_i[tid] = (int)0x80000000;   // INT_MIN
  }
  for (int i = tid; i < FEAT_DIM * EMBED_DIM; i += 1024) {
    int j = i >> 6, f = i & 63;
    W1T[j * 64 + f] = W1[f * EMBED_DIM + j];
  }
  __syncthreads();
  if (tid == 0) *flag = sflag;
}

// logits[q][n] = relu(fv[n]@W1 + b1) . K2[q] + cq[q]; folds per-queue row-max
// via wave butterfly + one wave-wide atomicMax (order-independent -> deterministic).
__global__ __launch_bounds__(64) void k_logits(const float* __restrict__ fv,
    const float* __restrict__ b1, const float* __restrict__ W1T,
    const float* __restrict__ K2T, const float* __restrict__ cq,
    float* __restrict__ logits, int* __restrict__ rowmax_i) {
  int t = threadIdx.x;
  int n = blockIdx.x * 64 + t;
  bool act = n < N_CLAUSES;
  int nn = act ? n : (N_CLAUSES - 1);
  float r[FEAT_DIM];
  const float4* fp = (const float4*)(fv + (size_t)nn * FEAT_DIM);
#pragma unroll
  for (int i = 0; i < FEAT_DIM / 4; ++i) {
    float4 v = fp[i];
    r[4 * i] = v.x; r[4 * i + 1] = v.y; r[4 * i + 2] = v.z; r[4 * i + 3] = v.w;
  }
  float acc[NUM_QUEUES];
#pragma unroll
  for (int q = 0; q < NUM_QUEUES; ++q) acc[q] = cq[q];
#pragma unroll 4
  for (int j = 0; j < EMBED_DIM; ++j) {
    const float* w = W1T + j * 64;   // wave-uniform
    float t0 = 0.f, t1 = 0.f, t2 = 0.f, t3 = 0.f;
#pragma unroll
    for (int f = 0; f < FEAT_DIM; f += 4) {
      t0 = fmaf(r[f],     w[f],     t0);
      t1 = fmaf(r[f + 1], w[f + 1], t1);
      t2 = fmaf(r[f + 2], w[f + 2], t2);
      t3 = fmaf(r[f + 3], w[f + 3], t3);
    }
    float tt = fmaxf((t0 + t1) + (t2 + t3) + b1[j], 0.f);
    const float* k2 = K2T + j * 8;
#pragma unroll
    for (int q = 0; q < NUM_QUEUES; ++q) acc[q] = fmaf(tt, k2[q], acc[q]);
  }
  if (act) {
#pragma unroll
    for (int q = 0; q < NUM_QUEUES; ++q) logits[(size_t)q * N_CLAUSES + n] = acc[q];
  }
  // per-queue wave max (inactive lanes hold clamped duplicate of clause 49999 - valid)
  float mq = acc[0];
#pragma unroll
  for (int q = 1; q < NUM_QUEUES; ++q) { /* keep per-q separate */ }
  // butterfly each queue's max; after reduction all lanes hold the max, lane q commits q
  float red[NUM_QUEUES];
#pragma unroll
  for (int q = 0; q < NUM_QUEUES; ++q) {
    float m = acc[q];
#pragma unroll
    for (int o = 32; o > 0; o >>= 1) m = fmaxf(m, __shfl_xor(m, o, 64));
    red[q] = m;
  }
  if (t < NUM_QUEUES) atomicMax(&rowmax_i[t], enc_f(red[t]));
  (void)mq;
}

// Queue-major masked-softmax accumulation: 8 clauses/thread, e/es in regs,
// 16 steps per block, nontemporal mask stream, wave shfl reduce.
__global__ __launch_bounds__(256) void k_steps(const float* __restrict__ logits,
    const int* __restrict__ rowmax_i, const void* __restrict__ maskv,
    const int* __restrict__ flag, float4* __restrict__ part) {
  int chunk = blockIdx.x, q = blockIdx.y, g = blockIdx.z;
  int t = threadIdx.x, w = t >> 6;
  int base = chunk * CHUNK + 8 * t;
  bool act = base < N_CLAUSES;   // 8-aligned: all-or-none per thread
  float M = dec_f(rowmax_i[q]);
  float e[8], es[8];
#pragma unroll
  for (int j = 0; j < 8; ++j) { e[j] = 0.f; es[j] = 0.f; }
  if (act) {
    const float* lrow = logits + (size_t)q * N_CLAUSES + base;
    float4 l0 = *(const float4*)(lrow);
    float4 l1 = *(const float4*)(lrow + 4);
    float a[8] = {l0.x - M, l0.y - M, l0.z - M, l0.w - M,
                  l1.x - M, l1.y - M, l1.z - M, l1.w - M};
#pragma unroll
    for (int j = 0; j < 8; ++j) { e[j] = __expf(a[j]); es[j] = e[j] * a[j]; }
  }
  int k0 = g * KPG + w;
  int s0 = q + 8 * k0;                    // step stride per i is 32
  float4* pout = part + (size_t)chunk * NUM_STEPS;
  if (*flag != 0) {
    // ---- byte mask path: 8 bytes per step ----
    const unsigned char* mb = (const unsigned char*)maskv + (size_t)s0 * N_CLAUSES + base;
#pragma unroll 2
    for (int i = 0; i < 16; ++i) {
      float z = 0.f, s1 = 0.f, c = 0.f;
      if (act) {
        v2u m = __builtin_nontemporal_load((const v2u*)(mb + (size_t)32 * N_CLAUSES * i));
        unsigned mw[2] = {m.x, m.y};
#pragma unroll
        for (int h = 0; h < 2; ++h) {
#pragma unroll
          for (int k = 0; k < 4; ++k) {
            float bb = ((mw[h] >> (8 * k)) & 0xffu) ? 1.f : 0.f;
            int j = 4 * h + k;
            z = fmaf(bb, e[j], z);
            s1 = fmaf(bb, es[j], s1);
            c += bb;
          }
        }
      }
#pragma unroll
      for (int o = 32; o > 0; o >>= 1) {
        z += __shfl_xor(z, o, 64); s1 += __shfl_xor(s1, o, 64); c += __shfl_xor(c, o, 64);
      }
      if ((t & 63) == 0) pout[s0 + 32 * i] = make_float4(z, s1, c, 0.f);
    }
  } else {
    // ---- int32 mask path: two dwordx4 per step ----
    const int* mi = (const int*)maskv + (size_t)s0 * N_CLAUSES + base;
#pragma unroll 2
    for (int i = 0; i < 16; ++i) {
      float z = 0.f, s1 = 0.f, c = 0.f;
      if (act) {
        const int* p = mi + (size_t)32 * N_CLAUSES * i;
        v4u m0 = __builtin_nontemporal_load((const v4u*)p);
        v4u m1 = __builtin_nontemporal_load((const v4u*)(p + 4));
        unsigned mv[8] = {m0.x, m0.y, m0.z, m0.w, m1.x, m1.y, m1.z, m1.w};
#pragma unroll
        for (int j = 0; j < 8; ++j) {
          float bb = mv[j] ? 1.f : 0.f;
          z = fmaf(bb, e[j], z);
          s1 = fmaf(bb, es[j], s1);
          c += bb;
        }
      }
#pragma unroll
      for (int o = 32; o > 0; o >>= 1) {
        z += __shfl_xor(z, o, 64); s1 += __shfl_xor(s1, o, 64); c += __shfl_xor(c, o, 64);
      }
      if ((t & 63) == 0) pout[s0 + 32 * i] = make_float4(z, s1, c, 0.f);
    }
  }
}

// 32 blocks x 64 steps: wave w sums chunks e = w, w+4, ...; LDS-combine; wave 0
// computes the per-step loss term.
__global__ __launch_bounds__(256) void k_red(const float4* __restrict__ part,
    const float* __restrict__ logits, const int* __restrict__ rowmax_i,
    const float* __restrict__ rewards, const int* __restrict__ qi,
    const int* __restrict__ si, float* __restrict__ loss) {
  int t = threadIdx.x, w = t >> 6, lane = t & 63;
  int s = blockIdx.x * 64 + lane;
  float z = 0.f, s1 = 0.f, c = 0.f;
  for (int e = w; e < NCHUNK; e += 4) {
    float4 p = part[(size_t)e * NUM_STEPS + s];   // lanes contiguous in s
    z += p.x; s1 += p.y; c += p.z;
  }
  __shared__ float sZ[4][64], sS[4][64], sC[4][64];
  sZ[w][lane] = z; sS[w][lane] = s1; sC[w][lane] = c;
  __syncthreads();
  if (w == 0) {
    z  = sZ[0][lane] + sZ[1][lane] + sZ[2][lane] + sZ[3][lane];
    s1 = sS[0][lane] + sS[1][lane] + sS[2][lane] + sS[3][lane];
    c  = sC[0][lane] + sC[1][lane] + sC[2][lane] + sC[3][lane];
    int q = qi[s];
    float M = dec_f(rowmax_i[q]);
    float ssel = logits[(size_t)q * N_CLAUSES + si[s]];
    float logZ = logf(z);
    float ce = logZ - (ssel - M);          // = -log_softmax[sel]
    float me = (s1 / z - logZ) / logf(c);  // normalized minus-entropy
    loss[s] = rewards[s] * ce + ENTROPY_COEF * me;
  }
}

__global__ __launch_bounds__(256) void k_sum(const float* __restrict__ loss,
                                             float* __restrict__ out) {
  int tid = threadIdx.x;
  float v = 0.f;
  for (int i = tid; i < NUM_STEPS; i += 256) v += loss[i];
#pragma unroll
  for (int o = 32; o > 0; o >>= 1) v += __shfl_xor(v, o, 64);
  __shared__ float sv[4];
  if ((tid & 63) == 0) sv[tid >> 6] = v;
  __syncthreads();
  if (tid == 0) out[0] = sv[0] + sv[1] + sv[2] + sv[3];
}

extern "C" void kernel_launch(void* const* d_in, const int* in_sizes, int n_in,
                              void* d_out, int out_size, void* d_ws, size_t ws_size,
                              hipStream_t stream) {
  const float* fv      = (const float*)d_in[0];
  const float* W1      = (const float*)d_in[1];
  const float* b1      = (const float*)d_in[2];
  const float* W2      = (const float*)d_in[3];
  const float* b2      = (const float*)d_in[4];
  const float* keys    = (const float*)d_in[5];
  const float* rewards = (const float*)d_in[6];
  const void*  mask    = d_in[7];
  const int*   queue_i = (const int*)d_in[8];
  const int*   sel_i   = (const int*)d_in[9];
  float* out = (float*)d_out;
  float* ws  = (float*)d_ws;

  float*  logits   = ws + WS_LOGITS;
  int*    rowmax_i = (int*)(ws + WS_ROWMAX);
  float*  K2T      = ws + WS_K2T;
  float*  cq       = ws + WS_CQ;
  float*  W1T      = ws + WS_W1T;
  int*    flag     = (int*)(ws + WS_FLAG);
  float4* part     = (float4*)(ws + WS_PART);
  float*  loss     = ws + WS_LOSS;

  hipLaunchKernelGGL(k_prep, dim3(1), dim3(1024), 0, stream,
                     W1, b2, W2, keys, (const unsigned int*)mask, W1T, K2T, cq, flag, rowmax_i);
  hipLaunchKernelGGL(k_logits, dim3((N_CLAUSES + 63) / 64), dim3(64), 0, stream,
                     fv, b1, W1T, K2T, cq, logits, rowmax_i);
  hipLaunchKernelGGL(k_steps, dim3(NCHUNK, NUM_QUEUES, SGRP), dim3(256), 0, stream,
                     logits, rowmax_i, mask, flag, part);
  hipLaunchKernelGGL(k_red, dim3(NUM_STEPS / 64), dim3(256), 0, stream,
                     part, logits, rowmax_i, rewards, queue_i, sel_i, loss);
  hipLaunchKernelGGL(k_sum, dim3(1), dim3(256), 0, stream, loss, out);
}